// Round 1
// 689.823 us; speedup vs baseline: 1.0026x; 1.0026x over previous
//
#include <hip/hip_runtime.h>

#define DIM 1536
#define NH 12
#define HD 128
#define S_LEN 5400
#define SPAD 5440      // 85*64  (kv tiles)
#define MPAD 5504      // 43*128 (GEMM M tiles / flash q tiles)
#define NQKV 4608
#define EPS_NORM 1e-6f

typedef __bf16 bf16_t;
typedef __bf16 bf16x8 __attribute__((ext_vector_type(8)));
typedef __bf16 bf16x4 __attribute__((ext_vector_type(4)));
typedef float  f32x4  __attribute__((ext_vector_type(4)));
typedef float  f32x16 __attribute__((ext_vector_type(16)));

// async global->LDS, 16B per lane; LDS dest is wave-uniform base + lane*16
#define GLOAD_LDS16(gp, lp) __builtin_amdgcn_global_load_lds( \
    (__attribute__((address_space(1))) void*)(void*)(gp),     \
    (__attribute__((address_space(3))) void*)(lp), 16, 0, 0)

// ---------------- conversion kernels ----------------

__global__ __launch_bounds__(256) void cvt_x_kernel(const float* __restrict__ x,
                                                    bf16_t* __restrict__ xb) {
  size_t base = ((size_t)blockIdx.x * 256 + threadIdx.x) * 4;
  if (base >= (size_t)MPAD * DIM) return;
  size_t row = base / DIM;
  float4 v = make_float4(0.f, 0.f, 0.f, 0.f);
  if (row < S_LEN) v = *(const float4*)&x[base];
  bf16x4 o; o[0] = (__bf16)v.x; o[1] = (__bf16)v.y; o[2] = (__bf16)v.z; o[3] = (__bf16)v.w;
  *(bf16x4*)&xb[base] = o;
}

__global__ __launch_bounds__(256) void cvt_wqkv_kernel(const float* __restrict__ qw,
                                                       const float* __restrict__ kw,
                                                       const float* __restrict__ vw,
                                                       bf16_t* __restrict__ wb) {
  size_t base = ((size_t)blockIdx.x * 256 + threadIdx.x) * 4;
  if (base >= (size_t)NQKV * DIM) return;
  int row = (int)(base / DIM);
  int col = (int)(base - (size_t)row * DIM);
  const float* src; int rr = row;
  if (rr >= 3072)      { src = vw; rr -= 3072; }
  else if (rr >= 1536) { src = kw; rr -= 1536; }
  else                 { src = qw; }
  float4 v = *(const float4*)&src[(size_t)rr * DIM + col];
  bf16x4 o; o[0] = (__bf16)v.x; o[1] = (__bf16)v.y; o[2] = (__bf16)v.z; o[3] = (__bf16)v.w;
  *(bf16x4*)&wb[base] = o;
}

__global__ __launch_bounds__(256) void cvt_wo_kernel(const float* __restrict__ w,
                                                     bf16_t* __restrict__ wb) {
  size_t base = ((size_t)blockIdx.x * 256 + threadIdx.x) * 4;
  if (base >= (size_t)DIM * DIM) return;
  float4 v = *(const float4*)&w[base];
  bf16x4 o; o[0] = (__bf16)v.x; o[1] = (__bf16)v.y; o[2] = (__bf16)v.z; o[3] = (__bf16)v.w;
  *(bf16x4*)&wb[base] = o;
}

// ---------------- GEMM: C[M,N] = A[M,K] @ B[N,K]^T + bias ----------------
// 2-phase pipeline: prefetch k-tile t+1 into buf^1 while computing buf, one
// raw barrier + vmcnt(0) drain per K-step (T3-minimum recipe).

template<bool OUT_BF16>
__global__ __launch_bounds__(256) void gemm_bt_kernel(
    const bf16_t* __restrict__ A, const bf16_t* __restrict__ B, void* __restrict__ C,
    const float* __restrict__ bias0, const float* __restrict__ bias1,
    const float* __restrict__ bias2, int M, int N, int K, int Mvalid) {
  __shared__ bf16_t As[2][128 * 32];
  __shared__ bf16_t Bs[2][128 * 32];
  int tid = threadIdx.x;
  int lane = tid & 63, wave = tid >> 6, quad = lane >> 4, l16 = lane & 15;
  int m0 = blockIdx.y * 128, n0 = blockIdx.x * 128;
  int wm = (wave >> 1) * 64, wn = (wave & 1) * 64;
  const bf16_t* Ab = A + (size_t)m0 * K;
  const bf16_t* Bb = B + (size_t)n0 * K;
  f32x4 acc[4][4] = {};

  int eo0 = tid * 8;
  int row0 = eo0 >> 5, col0 = eo0 & 31;
  int eo1 = (256 + tid) * 8;
  int row1 = eo1 >> 5, col1 = eo1 & 31;

  // prologue: stage k-tile 0 into buf 0
  GLOAD_LDS16(Ab + (size_t)row0 * K + col0, &As[0][eo0]);
  GLOAD_LDS16(Bb + (size_t)row0 * K + col0, &Bs[0][eo0]);
  GLOAD_LDS16(Ab + (size_t)row1 * K + col1, &As[0][eo1]);
  GLOAD_LDS16(Bb + (size_t)row1 * K + col1, &Bs[0][eo1]);
  asm volatile("s_waitcnt vmcnt(0)" ::: "memory");
  __builtin_amdgcn_s_barrier();
  __builtin_amdgcn_sched_barrier(0);

  int KT = K >> 5;
  for (int t = 0; t < KT; t++) {
    int cur = t & 1;
    if (t + 1 < KT) {
      int kn = (t + 1) << 5;
      GLOAD_LDS16(Ab + (size_t)row0 * K + kn + col0, &As[cur ^ 1][eo0]);
      GLOAD_LDS16(Bb + (size_t)row0 * K + kn + col0, &Bs[cur ^ 1][eo0]);
      GLOAD_LDS16(Ab + (size_t)row1 * K + kn + col1, &As[cur ^ 1][eo1]);
      GLOAD_LDS16(Bb + (size_t)row1 * K + kn + col1, &Bs[cur ^ 1][eo1]);
    }
    bf16x8 af[4], bfr[4];
#pragma unroll
    for (int i = 0; i < 4; i++)
      af[i] = *(const bf16x8*)&As[cur][(wm + i * 16 + l16) * 32 + quad * 8];
#pragma unroll
    for (int j = 0; j < 4; j++)
      bfr[j] = *(const bf16x8*)&Bs[cur][(wn + j * 16 + l16) * 32 + quad * 8];
#pragma unroll
    for (int i = 0; i < 4; i++)
#pragma unroll
      for (int j = 0; j < 4; j++)
        acc[i][j] = __builtin_amdgcn_mfma_f32_16x16x32_bf16(af[i], bfr[j], acc[i][j], 0, 0, 0);
    asm volatile("s_waitcnt vmcnt(0) lgkmcnt(0)" ::: "memory");
    __builtin_amdgcn_s_barrier();
    __builtin_amdgcn_sched_barrier(0);
  }
  // epilogue: C/D layout col=lane&15, row=quad*4+reg  [m89-verified]
#pragma unroll
  for (int j = 0; j < 4; j++) {
    int n = n0 + wn + j * 16 + l16;
    float bias = (n < 1536) ? bias0[n] : (n < 3072) ? bias1[n - 1536] : bias2[n - 3072];
#pragma unroll
    for (int i = 0; i < 4; i++) {
#pragma unroll
      for (int r = 0; r < 4; r++) {
        int m = m0 + wm + i * 16 + quad * 4 + r;
        float v = acc[i][j][r] + bias;
        if (OUT_BF16) {
          ((bf16_t*)C)[(size_t)m * N + n] = (__bf16)v;
        } else {
          if (m < Mvalid) ((float*)C)[(size_t)m * N + n] = v;
        }
      }
    }
  }
}

// ---------------- RMSNorm + RoPE for q,k ----------------
// q additionally pre-scaled by 1/sqrt(HD) so flash logits need no scale.

__global__ __launch_bounds__(256) void rope_qk_kernel(
    const bf16_t* __restrict__ qkv, const float* __restrict__ nqw,
    const float* __restrict__ nkw, const float* __restrict__ fcos,
    const float* __restrict__ fsin, bf16_t* __restrict__ qout,
    bf16_t* __restrict__ kout) {
  int s = blockIdx.x;              // 0..MPAD-1
  int tid = threadIdx.x;
  bool valid = s < S_LEN;
  int f = s / 900, hh = (s / 30) % 30, ww = s % 30;
  __shared__ float red[4];
  for (int which = 0; which < 2; which++) {
    const bf16_t* src = qkv + (size_t)s * NQKV + which * DIM;
    const float* nw = which ? nkw : nqw;
    bf16_t* dst = (which ? kout : qout) + (size_t)s * DIM;
    float osc = which ? 1.0f : 0.08838834764831845f;   // 1/sqrt(128) folded into q
    float v[6]; float ss = 0.f;
#pragma unroll
    for (int i = 0; i < 6; i++) {
      v[i] = valid ? (float)src[tid * 6 + i] : 0.f;
      ss += v[i] * v[i];
    }
#pragma unroll
    for (int off = 32; off >= 1; off >>= 1) ss += __shfl_down(ss, off);
    if ((tid & 63) == 0) red[tid >> 6] = ss;
    __syncthreads();
    float tot = red[0] + red[1] + red[2] + red[3];
    float rn = rsqrtf(tot * (1.f / DIM) + EPS_NORM);
    __syncthreads();   // protect red[] before next `which` iteration
#pragma unroll
    for (int i = 0; i < 3; i++) {
      int e0 = tid * 6 + 2 * i;
      int p = e0 >> 1;             // pair index; cc = p&63
      int cc = p & 63;
      int pos = (cc < 22) ? f : (cc < 43) ? hh : ww;  // split [22,21,21]
      float c = fcos[pos * 64 + cc], sn = fsin[pos * 64 + cc];
      float xr = v[2 * i] * rn * nw[e0];
      float xi = v[2 * i + 1] * rn * nw[e0 + 1];
      dst[e0]     = (__bf16)((xr * c - xi * sn) * osc);
      dst[e0 + 1] = (__bf16)((xr * sn + xi * c) * osc);
    }
  }
}

// ---------------- V transpose: qkv v-part -> vt[h][d][s] ----------------

__global__ __launch_bounds__(256) void v_transpose_kernel(const bf16_t* __restrict__ qkv,
                                                          bf16_t* __restrict__ vt) {
  __shared__ bf16_t tile[64][136];   // +8 pad
  int h = blockIdx.y, s0 = blockIdx.x * 64, tid = threadIdx.x;
#pragma unroll
  for (int it = 0; it < 4; it++) {
    int eo = (it * 256 + tid) * 8;   // 64x128 elements
    int row = eo >> 7, col = eo & 127;
    int s = s0 + row;
    bf16x8 val = {};
    if (s < S_LEN) val = *(const bf16x8*)&qkv[(size_t)s * NQKV + 3072 + h * HD + col];
    *(bf16x8*)&tile[row][col] = val;
  }
  __syncthreads();
  int d = tid & 127, j0 = (tid >> 7) * 32;
  bf16x8 outv[4];
#pragma unroll
  for (int b = 0; b < 4; b++)
#pragma unroll
    for (int j = 0; j < 8; j++) outv[b][j] = tile[j0 + b * 8 + j][d];
  size_t base = ((size_t)h * HD + d) * SPAD + s0 + j0;
#pragma unroll
  for (int b = 0; b < 4; b++) *(bf16x8*)&vt[base + b * 8] = outv[b];
}

// ---------------- flash attention (S^T = K Q^T, 32x32x16 MFMA) ----------------
// grid (43 q-tiles of 128, 12 heads); 256 threads = 4 waves, wave owns 32 q.
// 2-phase pipeline: K/V tiles double-buffered; prefetch t+1 issued before
// compute of t; single raw barrier + vmcnt(0) drain per tile (T3-minimum).
// C/D 32x32 layout: col=lane&31, row=(reg&3)+8*(reg>>2)+4*(lane>>5)  [m74/m101]
// A/B frag: row/col=lane&31, k=(lane>>5)*8+j.
// Softmax per-lane (q=lane&31): one shfl_xor(32) each for max/sum; defer-max
// rescale (THR=8, T13) skips the O-rescale when the running max barely grows.
// P transform via per-wave swizzled LDS buffer (b64 granularity).

__global__ __launch_bounds__(256, 2) void flash_attn_kernel(
    const bf16_t* __restrict__ q, const bf16_t* __restrict__ k,
    const bf16_t* __restrict__ vt, bf16_t* __restrict__ o) {
  __shared__ bf16_t Ks[2][64 * 128];   // 2x16 KB: [kv 64][k 128], 16B chunk c at pc = c^(row&15)
  __shared__ bf16_t Vs[2][64 * 128];   // 2x16 KB: row r holds d=2r,2r+1; chunk c'=(d&1)*8+(kv>>3), pc=c'^(r&15)
  __shared__ bf16_t Pw[4][32 * 64];    // 16 KB: per-wave [q 32][kv 64], 8B chunk c8=kv>>2 at pc8=c8^(q&15)
  int head = blockIdx.y;
  int s0 = blockIdx.x * 128;
  int tid = threadIdx.x, w = tid >> 6, lane = tid & 63;
  int l31 = lane & 31, hh = lane >> 5;

  // ---- Q B-frags from global (loop-invariant, 85x reuse): B[col=q][k=16kc+8hh+j]
  bf16x8 bq[8];
  {
    const bf16_t* qp = &q[(size_t)(s0 + w * 32 + l31) * DIM + head * HD + hh * 8];
#pragma unroll
    for (int kc = 0; kc < 8; kc++) bq[kc] = *(const bf16x8*)(qp + kc * 16);
  }

  float m_i = -1e30f, l_i = 0.f;
  f32x16 oacc[4] = {};   // O^T: d = dt*32 + (r&3)+8*(r>>2)+4*hh, col q = l31

  const int NT = SPAD / 64;   // 85

  // ---- prologue: stage tile 0 into buf 0
#pragma unroll
  for (int it = 0; it < 4; it++) {
    int slot = it * 256 + tid;
    int row = slot >> 4, pc = slot & 15;
    int c = pc ^ (row & 15);
    GLOAD_LDS16(k + (size_t)row * DIM + head * HD + c * 8, &Ks[0][slot * 8]);
  }
#pragma unroll
  for (int it = 0; it < 4; it++) {
    int slot = it * 256 + tid;
    int row = slot >> 4, pc = slot & 15;
    int cp = pc ^ (row & 15);
    int d = 2 * row + (cp >> 3);
    GLOAD_LDS16(vt + ((size_t)head * HD + d) * SPAD + (cp & 7) * 8, &Vs[0][slot * 8]);
  }
  asm volatile("s_waitcnt vmcnt(0)" ::: "memory");
  __builtin_amdgcn_s_barrier();
  __builtin_amdgcn_sched_barrier(0);

  for (int t = 0; t < NT; t++) {
    int kt = t * 64;
    int cur = t & 1;

    // ---- prefetch tile t+1 into buf cur^1 (stays in flight through compute)
    if (t + 1 < NT) {
      int kn = kt + 64;
#pragma unroll
      for (int it = 0; it < 4; it++) {
        int slot = it * 256 + tid;
        int row = slot >> 4, pc = slot & 15;
        int c = pc ^ (row & 15);
        GLOAD_LDS16(k + (size_t)(kn + row) * DIM + head * HD + c * 8, &Ks[cur ^ 1][slot * 8]);
      }
#pragma unroll
      for (int it = 0; it < 4; it++) {
        int slot = it * 256 + tid;
        int row = slot >> 4, pc = slot & 15;
        int cp = pc ^ (row & 15);
        int d = 2 * row + (cp >> 3);
        GLOAD_LDS16(vt + ((size_t)head * HD + d) * SPAD + kn + (cp & 7) * 8, &Vs[cur ^ 1][slot * 8]);
      }
    }

    // ---- S^T = K Q^T : 2 kv-tiles x 8 k-chunks of 32x32x16
    f32x16 sacc[2] = {};
    __builtin_amdgcn_s_setprio(1);
#pragma unroll
    for (int ns = 0; ns < 2; ns++) {
      int row = ns * 32 + l31;
#pragma unroll
      for (int kc = 0; kc < 8; kc++) {
        int pc = (kc * 2 + hh) ^ (row & 15);
        bf16x8 ak = *(const bf16x8*)&Ks[cur][row * 128 + pc * 8];
        sacc[ns] = __builtin_amdgcn_mfma_f32_32x32x16_bf16(ak, bq[kc], sacc[ns], 0, 0, 0);
      }
    }
    __builtin_amdgcn_s_setprio(0);

    // ---- mask (final tile only)
    if (kt + 64 > S_LEN) {
#pragma unroll
      for (int ns = 0; ns < 2; ns++)
#pragma unroll
        for (int r = 0; r < 16; r++) {
          int kvg = kt + ns * 32 + (r & 3) + 8 * (r >> 2) + 4 * hh;
          if (kvg >= S_LEN) sacc[ns][r] = -1e30f;
        }
    }

    // ---- online softmax with defer-max (THR=8)
    float mx = -1e30f;
#pragma unroll
    for (int ns = 0; ns < 2; ns++)
#pragma unroll
      for (int r = 0; r < 16; r++) mx = fmaxf(mx, sacc[ns][r]);
    mx = fmaxf(mx, __shfl_xor(mx, 32));
    if (!__all(mx - m_i <= 8.f)) {
      float mn = fmaxf(m_i, mx);
      float al = __expf(m_i - mn);
      l_i *= al;
#pragma unroll
      for (int dt = 0; dt < 4; dt++)
#pragma unroll
        for (int r = 0; r < 16; r++) oacc[dt][r] *= al;
      m_i = mn;
    }
    float rs = 0.f;
#pragma unroll
    for (int ns = 0; ns < 2; ns++)
#pragma unroll
      for (int r = 0; r < 16; r++) {
        float p = __expf(sacc[ns][r] - m_i);
        rs += p;
        sacc[ns][r] = p;
      }
    rs += __shfl_xor(rs, 32);
    l_i += rs;

    // ---- P -> per-wave LDS [q][kv] (b64 chunks, swizzled)
#pragma unroll
    for (int ns = 0; ns < 2; ns++)
#pragma unroll
      for (int tt = 0; tt < 4; tt++) {
        bf16x4 pk;
#pragma unroll
        for (int r4 = 0; r4 < 4; r4++) pk[r4] = (__bf16)sacc[ns][tt * 4 + r4];
        int c8 = ns * 8 + 2 * tt + hh;          // kv chunk (ns*32 + 8t + 4hh)/4
        int pc8 = c8 ^ (l31 & 15);
        *(bf16x4*)&Pw[w][l31 * 64 + pc8 * 4] = pk;
      }

    // ---- O^T += V^T P^T : 4 d-tiles x 4 kv-chunks of 32x32x16
    __builtin_amdgcn_s_setprio(1);
#pragma unroll
    for (int kvc = 0; kvc < 4; kvc++) {
      int c8a = kvc * 4 + hh * 2;
      bf16x4 plo = *(const bf16x4*)&Pw[w][l31 * 64 + ((c8a) ^ (l31 & 15)) * 4];
      bf16x4 phi = *(const bf16x4*)&Pw[w][l31 * 64 + ((c8a + 1) ^ (l31 & 15)) * 4];
      bf16x8 bp;
#pragma unroll
      for (int j = 0; j < 4; j++) { bp[j] = plo[j]; bp[j + 4] = phi[j]; }
#pragma unroll
      for (int dt = 0; dt < 4; dt++) {
        int d = dt * 32 + l31;
        int r = d >> 1;
        int cp = ((d & 1) << 3) | (kvc * 2 + hh);
        int pc = cp ^ (r & 15);
        bf16x8 av = *(const bf16x8*)&Vs[cur][r * 128 + pc * 8];
        oacc[dt] = __builtin_amdgcn_mfma_f32_32x32x16_bf16(av, bp, oacc[dt], 0, 0, 0);
      }
    }
    __builtin_amdgcn_s_setprio(0);

    // ---- end of tile: prefetch must have landed; all reads of buf cur done
    asm volatile("s_waitcnt vmcnt(0) lgkmcnt(0)" ::: "memory");
    __builtin_amdgcn_s_barrier();
    __builtin_amdgcn_sched_barrier(0);
  }

  // ---- epilogue: O^T -> per-wave LDS transpose (2 halves of 64 d) -> global
  float inv = 1.f / l_i;
  int qr = lane >> 1, seg = lane & 1;
  int srow = s0 + w * 32 + qr;
#pragma unroll
  for (int half = 0; half < 2; half++) {
#pragma unroll
    for (int dl = 0; dl < 2; dl++) {
      int dt = half * 2 + dl;
#pragma unroll
      for (int tt = 0; tt < 4; tt++) {
        bf16x4 v;
#pragma unroll
        for (int r4 = 0; r4 < 4; r4++) v[r4] = (__bf16)(oacc[dt][tt * 4 + r4] * inv);
        int c8 = dl * 8 + 2 * tt + hh;          // d chunk (dl*32 + 8t + 4hh)/4
        int pc8 = c8 ^ (l31 & 15);
        *(bf16x4*)&Pw[w][l31 * 64 + pc8 * 4] = v;
      }
    }
    // same-wave DS ordering guarantees write->read visibility
#pragma unroll
    for (int i = 0; i < 4; i++) {
      int c8 = seg * 8 + 2 * i;
      bf16x4 lo = *(const bf16x4*)&Pw[w][qr * 64 + ((c8) ^ (qr & 15)) * 4];
      bf16x4 hi = *(const bf16x4*)&Pw[w][qr * 64 + ((c8 + 1) ^ (qr & 15)) * 4];
      bf16x8 val;
#pragma unroll
      for (int j = 0; j < 4; j++) { val[j] = lo[j]; val[j + 4] = hi[j]; }
      if (srow < S_LEN)
        *(bf16x8*)&o[(size_t)srow * DIM + head * HD + half * 64 + seg * 32 + i * 8] = val;
    }
    __syncthreads();   // Pw reused across halves
  }
}

// ---------------- launch ----------------

extern "C" void kernel_launch(void* const* d_in, const int* in_sizes, int n_in,
                              void* d_out, int out_size, void* d_ws, size_t ws_size,
                              hipStream_t stream) {
  const float* x    = (const float*)d_in[0];
  const float* q_w  = (const float*)d_in[1];
  const float* q_b  = (const float*)d_in[2];
  const float* k_w  = (const float*)d_in[3];
  const float* k_b  = (const float*)d_in[4];
  const float* v_w  = (const float*)d_in[5];
  const float* v_b  = (const float*)d_in[6];
  const float* o_w  = (const float*)d_in[7];
  const float* o_b  = (const float*)d_in[8];
  const float* nqw  = (const float*)d_in[9];
  const float* nkw  = (const float*)d_in[10];
  const float* fcos = (const float*)d_in[11];
  const float* fsin = (const float*)d_in[12];

  char* ws = (char*)d_ws;
  bf16_t* xb   = (bf16_t*)(ws + 0);
  bf16_t* wqkv = (bf16_t*)(ws + 16908288);
  bf16_t* wob  = (bf16_t*)(ws + 31064064);
  bf16_t* qkv  = (bf16_t*)(ws + 35782656);
  bf16_t* qb   = (bf16_t*)(ws + 86507520);
  bf16_t* kb   = (bf16_t*)(ws + 103415808);
  bf16_t* vtb  = (bf16_t*)(ws + 0);         // alias xb (dead after GEMM1)
  bf16_t* aob  = (bf16_t*)(ws + 35782656);  // alias qkv (dead after rope+transpose)

  cvt_x_kernel<<<(MPAD * DIM / 4 + 255) / 256, 256, 0, stream>>>(x, xb);
  cvt_wqkv_kernel<<<(NQKV * DIM / 4 + 255) / 256, 256, 0, stream>>>(q_w, k_w, v_w, wqkv);
  cvt_wo_kernel<<<(DIM * DIM / 4 + 255) / 256, 256, 0, stream>>>(o_w, wob);

  gemm_bt_kernel<true><<<dim3(NQKV / 128, MPAD / 128), 256, 0, stream>>>(
      xb, wqkv, qkv, q_b, k_b, v_b, MPAD, NQKV, DIM, MPAD);

  rope_qk_kernel<<<MPAD, 256, 0, stream>>>(qkv, nqw, nkw, fcos, fsin, qb, kb);
  v_transpose_kernel<<<dim3(SPAD / 64, NH), 256, 0, stream>>>(qkv, vtb);

  flash_attn_kernel<<<dim3(MPAD / 128, NH), 256, 0, stream>>>(qb, kb, vtb, aob);

  gemm_bt_kernel<false><<<dim3(DIM / 128, MPAD / 128), 256, 0, stream>>>(
      aob, wob, d_out, o_b, o_b, o_b, MPAD, DIM, DIM, S_LEN);
}

// Round 3
// 657.470 us; speedup vs baseline: 1.0519x; 1.0492x over previous
//
#include <hip/hip_runtime.h>

#define DIM 1536
#define NH 12
#define HD 128
#define S_LEN 5400
#define SPAD 5440      // 85*64  (kv tiles)
#define MPAD 5504      // 43*128 (GEMM M tiles / flash q tiles)
#define NQKV 4608
#define EPS_NORM 1e-6f

typedef __bf16 bf16_t;
typedef __bf16 bf16x8 __attribute__((ext_vector_type(8)));
typedef __bf16 bf16x4 __attribute__((ext_vector_type(4)));
typedef __bf16 bf16x2 __attribute__((ext_vector_type(2)));
typedef float  f32x4  __attribute__((ext_vector_type(4)));
typedef float  f32x16 __attribute__((ext_vector_type(16)));
typedef int    i32x2  __attribute__((ext_vector_type(2)));

// async global->LDS, 16B per lane; LDS dest is wave-uniform base + lane*16
#define GLOAD_LDS16(gp, lp) __builtin_amdgcn_global_load_lds( \
    (__attribute__((address_space(1))) void*)(void*)(gp),     \
    (__attribute__((address_space(3))) void*)(lp), 16, 0, 0)

// pack two f32 -> bf16x2 word (compiler emits cvt_pk; don't hand-write asm, m240)
__device__ __forceinline__ unsigned int pkbf(float a, float b) {
  union { bf16x2 h; unsigned int u; } c;
  c.h[0] = (__bf16)a; c.h[1] = (__bf16)b;
  return c.u;
}

// cross-half (lane ^ 32) reduce via permlane32_swap BUILTIN (two modeled defs,
// no register-coalescing hazard; max/sum of the result pair is direction-agnostic)
__device__ __forceinline__ float xhalf_max(float x) {
  i32x2 r = __builtin_amdgcn_permlane32_swap(__float_as_int(x), __float_as_int(x),
                                             false, false);
  return fmaxf(__int_as_float(r.x), __int_as_float(r.y));
}
__device__ __forceinline__ float xhalf_sum(float x) {
  i32x2 r = __builtin_amdgcn_permlane32_swap(__float_as_int(x), __float_as_int(x),
                                             false, false);
  return __int_as_float(r.x) + __int_as_float(r.y);
}

// ---------------- conversion kernels ----------------

__global__ __launch_bounds__(256) void cvt_x_kernel(const float* __restrict__ x,
                                                    bf16_t* __restrict__ xb) {
  size_t base = ((size_t)blockIdx.x * 256 + threadIdx.x) * 4;
  if (base >= (size_t)MPAD * DIM) return;
  size_t row = base / DIM;
  float4 v = make_float4(0.f, 0.f, 0.f, 0.f);
  if (row < S_LEN) v = *(const float4*)&x[base];
  bf16x4 o; o[0] = (__bf16)v.x; o[1] = (__bf16)v.y; o[2] = (__bf16)v.z; o[3] = (__bf16)v.w;
  *(bf16x4*)&xb[base] = o;
}

__global__ __launch_bounds__(256) void cvt_wqkv_kernel(const float* __restrict__ qw,
                                                       const float* __restrict__ kw,
                                                       const float* __restrict__ vw,
                                                       bf16_t* __restrict__ wb) {
  size_t base = ((size_t)blockIdx.x * 256 + threadIdx.x) * 4;
  if (base >= (size_t)NQKV * DIM) return;
  int row = (int)(base / DIM);
  int col = (int)(base - (size_t)row * DIM);
  const float* src; int rr = row;
  if (rr >= 3072)      { src = vw; rr -= 3072; }
  else if (rr >= 1536) { src = kw; rr -= 1536; }
  else                 { src = qw; }
  float4 v = *(const float4*)&src[(size_t)rr * DIM + col];
  bf16x4 o; o[0] = (__bf16)v.x; o[1] = (__bf16)v.y; o[2] = (__bf16)v.z; o[3] = (__bf16)v.w;
  *(bf16x4*)&wb[base] = o;
}

__global__ __launch_bounds__(256) void cvt_wo_kernel(const float* __restrict__ w,
                                                     bf16_t* __restrict__ wb) {
  size_t base = ((size_t)blockIdx.x * 256 + threadIdx.x) * 4;
  if (base >= (size_t)DIM * DIM) return;
  float4 v = *(const float4*)&w[base];
  bf16x4 o; o[0] = (__bf16)v.x; o[1] = (__bf16)v.y; o[2] = (__bf16)v.z; o[3] = (__bf16)v.w;
  *(bf16x4*)&wb[base] = o;
}

// ---------------- GEMM: C[M,N] = A[M,K] @ B[N,K]^T + bias ----------------
// 2-phase pipeline: prefetch k-tile t+1 into buf^1 while computing buf.

template<bool OUT_BF16>
__global__ __launch_bounds__(256) void gemm_bt_kernel(
    const bf16_t* __restrict__ A, const bf16_t* __restrict__ B, void* __restrict__ C,
    const float* __restrict__ bias0, const float* __restrict__ bias1,
    const float* __restrict__ bias2, int M, int N, int K, int Mvalid) {
  __shared__ bf16_t As[2][128 * 32];
  __shared__ bf16_t Bs[2][128 * 32];
  int tid = threadIdx.x;
  int lane = tid & 63, wave = tid >> 6, quad = lane >> 4, l16 = lane & 15;
  int m0 = blockIdx.y * 128, n0 = blockIdx.x * 128;
  int wm = (wave >> 1) * 64, wn = (wave & 1) * 64;
  const bf16_t* Ab = A + (size_t)m0 * K;
  const bf16_t* Bb = B + (size_t)n0 * K;
  f32x4 acc[4][4] = {};

  int eo0 = tid * 8;
  int row0 = eo0 >> 5, col0 = eo0 & 31;
  int eo1 = (256 + tid) * 8;
  int row1 = eo1 >> 5, col1 = eo1 & 31;

  // prologue: stage k-tile 0 into buf 0
  GLOAD_LDS16(Ab + (size_t)row0 * K + col0, &As[0][eo0]);
  GLOAD_LDS16(Bb + (size_t)row0 * K + col0, &Bs[0][eo0]);
  GLOAD_LDS16(Ab + (size_t)row1 * K + col1, &As[0][eo1]);
  GLOAD_LDS16(Bb + (size_t)row1 * K + col1, &Bs[0][eo1]);
  asm volatile("s_waitcnt vmcnt(0)" ::: "memory");
  __builtin_amdgcn_s_barrier();
  __builtin_amdgcn_sched_barrier(0);

  int KT = K >> 5;
  for (int t = 0; t < KT; t++) {
    int cur = t & 1;
    if (t + 1 < KT) {
      int kn = (t + 1) << 5;
      GLOAD_LDS16(Ab + (size_t)row0 * K + kn + col0, &As[cur ^ 1][eo0]);
      GLOAD_LDS16(Bb + (size_t)row0 * K + kn + col0, &Bs[cur ^ 1][eo0]);
      GLOAD_LDS16(Ab + (size_t)row1 * K + kn + col1, &As[cur ^ 1][eo1]);
      GLOAD_LDS16(Bb + (size_t)row1 * K + kn + col1, &Bs[cur ^ 1][eo1]);
    }
    bf16x8 af[4], bfr[4];
#pragma unroll
    for (int i = 0; i < 4; i++)
      af[i] = *(const bf16x8*)&As[cur][(wm + i * 16 + l16) * 32 + quad * 8];
#pragma unroll
    for (int j = 0; j < 4; j++)
      bfr[j] = *(const bf16x8*)&Bs[cur][(wn + j * 16 + l16) * 32 + quad * 8];
#pragma unroll
    for (int i = 0; i < 4; i++)
#pragma unroll
      for (int j = 0; j < 4; j++)
        acc[i][j] = __builtin_amdgcn_mfma_f32_16x16x32_bf16(af[i], bfr[j], acc[i][j], 0, 0, 0);
    asm volatile("s_waitcnt vmcnt(0) lgkmcnt(0)" ::: "memory");
    __builtin_amdgcn_s_barrier();
    __builtin_amdgcn_sched_barrier(0);
  }
  // epilogue: C/D layout col=lane&15, row=quad*4+reg  [m89-verified]
#pragma unroll
  for (int j = 0; j < 4; j++) {
    int n = n0 + wn + j * 16 + l16;
    float bias = (n < 1536) ? bias0[n] : (n < 3072) ? bias1[n - 1536] : bias2[n - 3072];
#pragma unroll
    for (int i = 0; i < 4; i++) {
#pragma unroll
      for (int r = 0; r < 4; r++) {
        int m = m0 + wm + i * 16 + quad * 4 + r;
        float v = acc[i][j][r] + bias;
        if (OUT_BF16) {
          ((bf16_t*)C)[(size_t)m * N + n] = (__bf16)v;
        } else {
          if (m < Mvalid) ((float*)C)[(size_t)m * N + n] = v;
        }
      }
    }
  }
}

// ---------------- RMSNorm + RoPE for q,k ----------------
// q pre-scaled by (1/sqrt(HD)) * log2(e) so flash uses raw v_exp_f32 (2^x)
// with no per-element multiply and no logit scale.

__global__ __launch_bounds__(256) void rope_qk_kernel(
    const bf16_t* __restrict__ qkv, const float* __restrict__ nqw,
    const float* __restrict__ nkw, const float* __restrict__ fcos,
    const float* __restrict__ fsin, bf16_t* __restrict__ qout,
    bf16_t* __restrict__ kout) {
  int s = blockIdx.x;              // 0..MPAD-1
  int tid = threadIdx.x;
  bool valid = s < S_LEN;
  int f = s / 900, hh = (s / 30) % 30, ww = s % 30;
  __shared__ float red[4];
  for (int which = 0; which < 2; which++) {
    const bf16_t* src = qkv + (size_t)s * NQKV + which * DIM;
    const float* nw = which ? nkw : nqw;
    bf16_t* dst = (which ? kout : qout) + (size_t)s * DIM;
    // 0.12751742686 = (1/sqrt(128)) * log2(e)
    float osc = which ? 1.0f : 0.12751742686f;
    float v[6]; float ss = 0.f;
#pragma unroll
    for (int i = 0; i < 6; i++) {
      v[i] = valid ? (float)src[tid * 6 + i] : 0.f;
      ss += v[i] * v[i];
    }
#pragma unroll
    for (int off = 32; off >= 1; off >>= 1) ss += __shfl_down(ss, off);
    if ((tid & 63) == 0) red[tid >> 6] = ss;
    __syncthreads();
    float tot = red[0] + red[1] + red[2] + red[3];
    float rn = rsqrtf(tot * (1.f / DIM) + EPS_NORM);
    __syncthreads();   // protect red[] before next `which` iteration
#pragma unroll
    for (int i = 0; i < 3; i++) {
      int e0 = tid * 6 + 2 * i;
      int p = e0 >> 1;             // pair index; cc = p&63
      int cc = p & 63;
      int pos = (cc < 22) ? f : (cc < 43) ? hh : ww;  // split [22,21,21]
      float c = fcos[pos * 64 + cc], sn = fsin[pos * 64 + cc];
      float xr = v[2 * i] * rn * nw[e0];
      float xi = v[2 * i + 1] * rn * nw[e0 + 1];
      dst[e0]     = (__bf16)((xr * c - xi * sn) * osc);
      dst[e0 + 1] = (__bf16)((xr * sn + xi * c) * osc);
    }
  }
}

// ---------------- V transpose: qkv v-part -> vt[h][d][s] ----------------

__global__ __launch_bounds__(256) void v_transpose_kernel(const bf16_t* __restrict__ qkv,
                                                          bf16_t* __restrict__ vt) {
  __shared__ bf16_t tile[64][136];   // +8 pad
  int h = blockIdx.y, s0 = blockIdx.x * 64, tid = threadIdx.x;
#pragma unroll
  for (int it = 0; it < 4; it++) {
    int eo = (it * 256 + tid) * 8;   // 64x128 elements
    int row = eo >> 7, col = eo & 127;
    int s = s0 + row;
    bf16x8 val = {};
    if (s < S_LEN) val = *(const bf16x8*)&qkv[(size_t)s * NQKV + 3072 + h * HD + col];
    *(bf16x8*)&tile[row][col] = val;
  }
  __syncthreads();
  int d = tid & 127, j0 = (tid >> 7) * 32;
  bf16x8 outv[4];
#pragma unroll
  for (int b = 0; b < 4; b++)
#pragma unroll
    for (int j = 0; j < 8; j++) outv[b][j] = tile[j0 + b * 8 + j][d];
  size_t base = ((size_t)h * HD + d) * SPAD + s0 + j0;
#pragma unroll
  for (int b = 0; b < 4; b++) *(bf16x8*)&vt[base + b * 8] = outv[b];
}

// ---------------- flash attention (S^T = K Q^T, 32x32x16 MFMA) ----------------
// grid (43 q-tiles of 128, 12 heads); 256 threads = 4 waves, wave owns 32 q.
// 2-phase double-buffered K/V staging; single barrier + vmcnt(0) per tile.
//   * T12 in-register P: cvt_pk pairs + permlane32_swap BUILTIN -> PV B-operand
//     directly from sacc regs (no P LDS round-trip). Word mapping follows the
//     m214-v22-verified recipe: swap(w0,w2) -> {r.x = low-kv word, r.y = high}.
//   * cross-half max/sum via permlane32_swap builtin (direction-agnostic use).
//   * tree-shaped (depth-6) max/sum reductions.
//   * logits pre-scaled by log2(e): exp = raw v_exp_f32 (2^x); defer-max
//     threshold 11.5 (= 8 * log2 e).
// C/D 32x32 layout: col=lane&31, row=(reg&3)+8*(reg>>2)+4*(lane>>5)  [m74/m101]
// A/B frag: row/col=lane&31, k=(lane>>5)*8+j.

__global__ __launch_bounds__(256, 2) void flash_attn_kernel(
    const bf16_t* __restrict__ q, const bf16_t* __restrict__ k,
    const bf16_t* __restrict__ vt, bf16_t* __restrict__ o) {
  __shared__ bf16_t Ks[2][64 * 128];   // 2x16 KB: [kv 64][k 128], 16B chunk c at pc = c^(row&15)
  __shared__ bf16_t Vs[2][64 * 128];   // 2x16 KB: row r holds d=2r,2r+1; chunk c'=(d&1)*8+(kv>>3), pc=c'^(r&15)
  int head = blockIdx.y;
  int s0 = blockIdx.x * 128;
  int tid = threadIdx.x, w = tid >> 6, lane = tid & 63;
  int l31 = lane & 31, hh = lane >> 5;

  // ---- Q B-frags from global (loop-invariant, 85x reuse): B[col=q][k=16kc+8hh+j]
  bf16x8 bq[8];
  {
    const bf16_t* qp = &q[(size_t)(s0 + w * 32 + l31) * DIM + head * HD + hh * 8];
#pragma unroll
    for (int kc = 0; kc < 8; kc++) bq[kc] = *(const bf16x8*)(qp + kc * 16);
  }

  float m_i = -1e30f, l_i = 0.f;
  f32x16 oacc[4] = {};   // O^T: d = dt*32 + (r&3)+8*(r>>2)+4*hh, col q = l31

  const int NT = SPAD / 64;   // 85

  // ---- prologue: stage tile 0 into buf 0
#pragma unroll
  for (int it = 0; it < 4; it++) {
    int slot = it * 256 + tid;
    int row = slot >> 4, pc = slot & 15;
    int c = pc ^ (row & 15);
    GLOAD_LDS16(k + (size_t)row * DIM + head * HD + c * 8, &Ks[0][slot * 8]);
  }
#pragma unroll
  for (int it = 0; it < 4; it++) {
    int slot = it * 256 + tid;
    int row = slot >> 4, pc = slot & 15;
    int cp = pc ^ (row & 15);
    int d = 2 * row + (cp >> 3);
    GLOAD_LDS16(vt + ((size_t)head * HD + d) * SPAD + (cp & 7) * 8, &Vs[0][slot * 8]);
  }
  asm volatile("s_waitcnt vmcnt(0)" ::: "memory");
  __builtin_amdgcn_s_barrier();
  __builtin_amdgcn_sched_barrier(0);

  for (int t = 0; t < NT; t++) {
    int kt = t * 64;
    int cur = t & 1;

    // ---- prefetch tile t+1 into buf cur^1 (stays in flight through compute)
    if (t + 1 < NT) {
      int kn = kt + 64;
#pragma unroll
      for (int it = 0; it < 4; it++) {
        int slot = it * 256 + tid;
        int row = slot >> 4, pc = slot & 15;
        int c = pc ^ (row & 15);
        GLOAD_LDS16(k + (size_t)(kn + row) * DIM + head * HD + c * 8, &Ks[cur ^ 1][slot * 8]);
      }
#pragma unroll
      for (int it = 0; it < 4; it++) {
        int slot = it * 256 + tid;
        int row = slot >> 4, pc = slot & 15;
        int cp = pc ^ (row & 15);
        int d = 2 * row + (cp >> 3);
        GLOAD_LDS16(vt + ((size_t)head * HD + d) * SPAD + kn + (cp & 7) * 8, &Vs[cur ^ 1][slot * 8]);
      }
    }

    // ---- S^T = K Q^T : 2 kv-tiles x 8 k-chunks of 32x32x16
    f32x16 sacc[2] = {};
    __builtin_amdgcn_s_setprio(1);
#pragma unroll
    for (int ns = 0; ns < 2; ns++) {
      int row = ns * 32 + l31;
#pragma unroll
      for (int kc = 0; kc < 8; kc++) {
        int pc = (kc * 2 + hh) ^ (row & 15);
        bf16x8 ak = *(const bf16x8*)&Ks[cur][row * 128 + pc * 8];
        sacc[ns] = __builtin_amdgcn_mfma_f32_32x32x16_bf16(ak, bq[kc], sacc[ns], 0, 0, 0);
      }
    }
    __builtin_amdgcn_s_setprio(0);

    // ---- mask (final tile only)
    if (kt + 64 > S_LEN) {
#pragma unroll
      for (int ns = 0; ns < 2; ns++)
#pragma unroll
        for (int r = 0; r < 16; r++) {
          int kvg = kt + ns * 32 + (r & 3) + 8 * (r >> 2) + 4 * hh;
          if (kvg >= S_LEN) sacc[ns][r] = -1e30f;
        }
    }

    // ---- online softmax (log2 domain), tree max, permlane cross-half
    float mx;
    {
      float tm[8];
#pragma unroll
      for (int i = 0; i < 8; i++)
        tm[i] = fmaxf(fmaxf(sacc[0][i], sacc[0][i + 8]),
                      fmaxf(sacc[1][i], sacc[1][i + 8]));
#pragma unroll
      for (int i = 0; i < 4; i++) tm[i] = fmaxf(tm[i], tm[i + 4]);
      mx = fmaxf(fmaxf(tm[0], tm[2]), fmaxf(tm[1], tm[3]));
    }
    mx = xhalf_max(mx);
    if (!__all(mx - m_i <= 11.5f)) {   // 11.5 ~= 8*log2(e)
      float mn = fmaxf(m_i, mx);
      float al = __builtin_amdgcn_exp2f(m_i - mn);
      l_i *= al;
#pragma unroll
      for (int dt = 0; dt < 4; dt++)
#pragma unroll
        for (int r = 0; r < 16; r++) oacc[dt][r] *= al;
      m_i = mn;
    }
#pragma unroll
    for (int ns = 0; ns < 2; ns++)
#pragma unroll
      for (int r = 0; r < 16; r++)
        sacc[ns][r] = __builtin_amdgcn_exp2f(sacc[ns][r] - m_i);
    float rs;
    {
      float ts[8];
#pragma unroll
      for (int i = 0; i < 8; i++)
        ts[i] = (sacc[0][i] + sacc[0][i + 8]) + (sacc[1][i] + sacc[1][i + 8]);
#pragma unroll
      for (int i = 0; i < 4; i++) ts[i] += ts[i + 4];
      rs = (ts[0] + ts[2]) + (ts[1] + ts[3]);
    }
    l_i += xhalf_sum(rs);

    // ---- O^T += V^T P^T : in-register P (T12), 4 kv-chunks of 32x32x16
    // chunk kvc uses regs rb..rb+7 of sacc[kvc>>1], rb=(kvc&1)*8.
    // Lane needs bp[j] = P[q=l31][16*kvc + 8*hh + j]: comes from reg
    // rb + 4*hh + (j&3) held by the (j>>2)-half lane of the same l31.
    // swap(w0,w2): r.x = (lo: own w0, hi: lo-half's w2) = low-kv word;
    //              r.y = (lo: hi-half's w0, hi: own w2) = high-kv word.
    __builtin_amdgcn_s_setprio(1);
#pragma unroll
    for (int kvc = 0; kvc < 4; kvc++) {
      int ns = kvc >> 1, rb = (kvc & 1) * 8;
      int w0 = (int)pkbf(sacc[ns][rb + 0], sacc[ns][rb + 1]);
      int w1 = (int)pkbf(sacc[ns][rb + 2], sacc[ns][rb + 3]);
      int w2 = (int)pkbf(sacc[ns][rb + 4], sacc[ns][rb + 5]);
      int w3 = (int)pkbf(sacc[ns][rb + 6], sacc[ns][rb + 7]);
      i32x2 r02 = __builtin_amdgcn_permlane32_swap(w0, w2, false, false);
      i32x2 r13 = __builtin_amdgcn_permlane32_swap(w1, w3, false, false);
      union { unsigned int u[4]; bf16x8 v8; } bpu;
      bpu.u[0] = (unsigned int)r02.x; bpu.u[1] = (unsigned int)r13.x;
      bpu.u[2] = (unsigned int)r02.y; bpu.u[3] = (unsigned int)r13.y;
      bf16x8 bp = bpu.v8;
#pragma unroll
      for (int dt = 0; dt < 4; dt++) {
        int d = dt * 32 + l31;
        int r = d >> 1;
        int cp = ((d & 1) << 3) | (kvc * 2 + hh);
        int pc = cp ^ (r & 15);
        bf16x8 av = *(const bf16x8*)&Vs[cur][r * 128 + pc * 8];
        oacc[dt] = __builtin_amdgcn_mfma_f32_32x32x16_bf16(av, bp, oacc[dt], 0, 0, 0);
      }
    }
    __builtin_amdgcn_s_setprio(0);

    // ---- end of tile: prefetch must have landed; all reads of buf cur done
    asm volatile("s_waitcnt vmcnt(0) lgkmcnt(0)" ::: "memory");
    __builtin_amdgcn_s_barrier();
    __builtin_amdgcn_sched_barrier(0);
  }

  // ---- epilogue: O^T -> per-wave LDS transpose (scratch in dead Ks) -> global
  // All K/V LDS reads drained at the final loop barrier, so Ks is reusable.
  bf16_t* scr = ((bf16_t*)Ks) + w * (32 * 64);
  float inv = 1.f / l_i;
  int qr = lane >> 1, seg = lane & 1;
  int srow = s0 + w * 32 + qr;
#pragma unroll
  for (int half = 0; half < 2; half++) {
#pragma unroll
    for (int dl = 0; dl < 2; dl++) {
      int dt = half * 2 + dl;
#pragma unroll
      for (int tt = 0; tt < 4; tt++) {
        bf16x4 v;
#pragma unroll
        for (int r4 = 0; r4 < 4; r4++) v[r4] = (__bf16)(oacc[dt][tt * 4 + r4] * inv);
        int c8 = dl * 8 + 2 * tt + hh;          // d chunk (dl*32 + 8t + 4hh)/4
        int pc8 = c8 ^ (l31 & 15);
        *(bf16x4*)&scr[l31 * 64 + pc8 * 4] = v;
      }
    }
    // same-wave DS ordering guarantees write->read visibility (per-wave region)
#pragma unroll
    for (int i = 0; i < 4; i++) {
      int c8 = seg * 8 + 2 * i;
      bf16x4 lo = *(const bf16x4*)&scr[qr * 64 + ((c8) ^ (qr & 15)) * 4];
      bf16x4 hi = *(const bf16x4*)&scr[qr * 64 + ((c8 + 1) ^ (qr & 15)) * 4];
      bf16x8 val;
#pragma unroll
      for (int j = 0; j < 4; j++) { val[j] = lo[j]; val[j + 4] = hi[j]; }
      if (srow < S_LEN)
        *(bf16x8*)&o[(size_t)srow * DIM + head * HD + half * 64 + seg * 32 + i * 8] = val;
    }
  }
}

// ---------------- launch ----------------

extern "C" void kernel_launch(void* const* d_in, const int* in_sizes, int n_in,
                              void* d_out, int out_size, void* d_ws, size_t ws_size,
                              hipStream_t stream) {
  const float* x    = (const float*)d_in[0];
  const float* q_w  = (const float*)d_in[1];
  const float* q_b  = (const float*)d_in[2];
  const float* k_w  = (const float*)d_in[3];
  const float* k_b  = (const float*)d_in[4];
  const float* v_w  = (const float*)d_in[5];
  const float* v_b  = (const float*)d_in[6];
  const float* o_w  = (const float*)d_in[7];
  const float* o_b  = (const float*)d_in[8];
  const float* nqw  = (const float*)d_in[9];
  const float* nkw  = (const float*)d_in[10];
  const float* fcos = (const float*)d_in[11];
  const float* fsin = (const float*)d_in[12];

  char* ws = (char*)d_ws;
  bf16_t* xb   = (bf16_t*)(ws + 0);
  bf16_t* wqkv = (bf16_t*)(ws + 16908288);
  bf16_t* wob  = (bf16_t*)(ws + 31064064);
  bf16_t* qkv  = (bf16_t*)(ws + 35782656);
  bf16_t* qb   = (bf16_t*)(ws + 86507520);
  bf16_t* kb   = (bf16_t*)(ws + 103415808);
  bf16_t* vtb  = (bf16_t*)(ws + 0);         // alias xb (dead after GEMM1)
  bf16_t* aob  = (bf16_t*)(ws + 35782656);  // alias qkv (dead after rope+transpose)

  cvt_x_kernel<<<(MPAD * DIM / 4 + 255) / 256, 256, 0, stream>>>(x, xb);
  cvt_wqkv_kernel<<<(NQKV * DIM / 4 + 255) / 256, 256, 0, stream>>>(q_w, k_w, v_w, wqkv);
  cvt_wo_kernel<<<(DIM * DIM / 4 + 255) / 256, 256, 0, stream>>>(o_w, wob);

  gemm_bt_kernel<true><<<dim3(NQKV / 128, MPAD / 128), 256, 0, stream>>>(
      xb, wqkv, qkv, q_b, k_b, v_b, MPAD, NQKV, DIM, MPAD);

  rope_qk_kernel<<<MPAD, 256, 0, stream>>>(qkv, nqw, nkw, fcos, fsin, qb, kb);
  v_transpose_kernel<<<dim3(SPAD / 64, NH), 256, 0, stream>>>(qkv, vtb);

  flash_attn_kernel<<<dim3(MPAD / 128, NH), 256, 0, stream>>>(qb, kb, vtb, aob);

  gemm_bt_kernel<false><<<dim3(DIM / 128, MPAD / 128), 256, 0, stream>>>(
      aob, wob, d_out, o_b, o_b, o_b, MPAD, DIM, DIM, S_LEN);
}